// Round 7
// baseline (156.751 us; speedup 1.0000x reference)
//
#include <hip/hip_runtime.h>
#include <hip/hip_bf16.h>
#include <math.h>

#define DEVI __device__ __forceinline__

typedef _Float16 f16;
typedef f16 f16x2 __attribute__((ext_vector_type(2)));
typedef f16 f16x4 __attribute__((ext_vector_type(4)));
typedef f16 f16x8 __attribute__((ext_vector_type(8)));
typedef float f32x4 __attribute__((ext_vector_type(4)));

// ---- problem dims (fixed) ----
constexpr int Bb = 2, Hh = 32, Ww = 32, Dd = 32;
constexpr int Nn = Hh * Ww * Dd;      // 32768
constexpr int BN = Bb * Nn;           // 65536 tokens
constexpr int CIN = 160, CHH = 640;
constexpr int PD = 34;                // padded dim
constexpr int PT = PD * PD * PD;      // 39304 padded tokens per batch

// ---- workspace layout (bytes) ----
constexpr size_t W1_OFF  = 0;                                   // fc1_w f16: 204,800
constexpr size_t W2_OFF  = W1_OFF + (size_t)CHH * CIN * 2;      // fc2_w f16: 204,800
constexpr size_t WTH_OFF = W2_OFF + (size_t)CIN * CHH * 2;      // dw_w f16 [27][640]: 34,560
constexpr size_t ZP_OFF  = WTH_OFF + 34816;                     // zero page: 8,192
constexpr size_t U_OFF   = 458752;                              // h2 f16: 83,886,080
constexpr size_t H1P_OFF = U_OFF + (size_t)BN * CHH * 2;        // h1 padded f16: 100,618,240

DEVI void async16(const void* g, void* l) {
  __builtin_amdgcn_global_load_lds(
      (const __attribute__((address_space(1))) void*)g,
      (__attribute__((address_space(3))) void*)l, 16, 0, 0);
}

// ---- prep: weights -> f16, dw_w transpose -> f16, zero page ----
__global__ __launch_bounds__(256) void k_prep_w(const float* __restrict__ fc1w,
                                                const float* __restrict__ fc2w,
                                                const float* __restrict__ dww,
                                                f16* __restrict__ w1h,
                                                f16* __restrict__ w2h,
                                                f16* __restrict__ wTh,
                                                unsigned* __restrict__ zp) {
  int i = blockIdx.x * 256 + threadIdx.x;
  const int NW = CHH * CIN;  // 102400
  if (i < NW) {
    w1h[i] = (f16)fc1w[i];
  } else if (i < 2 * NW) {
    int j = i - NW;
    w2h[j] = (f16)fc2w[j];
  } else if (i < 2 * NW + 27 * CHH) {
    int j = i - 2 * NW;
    int ch = j / 27, tap = j % 27;
    wTh[tap * CHH + ch] = (f16)dww[j];
  } else if (i < 2 * NW + 27 * CHH + 2048) {
    zp[i - (2 * NW + 27 * CHH)] = 0u;
  }
}

// ---- zero the pad shell of the padded h1 volume (no input deps) ----
__global__ __launch_bounds__(256) void k_zero_pad(f16* __restrict__ h1p) {
  int g = blockIdx.x * 256 + threadIdx.x;   // over 2*PT*80
  int p = g / 80;
  int c = g - p * 80;
  if (p >= 2 * PT) return;
  int r = p % PT;
  int hp = r / (PD * PD);
  int r2 = r % (PD * PD);
  int wp = r2 / PD, dp = r2 % PD;
  bool pad = (hp == 0) | (hp == PD - 1) | (wp == 0) | (wp == PD - 1) |
             (dp == 0) | (dp == PD - 1);
  if (!pad) return;
  f16x8 z = {};
  *(f16x8*)&h1p[(size_t)p * CHH + c * 8] = z;
}

// ---- GEMM1 (fused x-convert + shift(H)): h1p = fc1 of shifted x ----
// Block: M=128 full-K A-panel staged ONCE in LDS (f32->f16 cvt in staging),
// then loops 5 N-tiles x 5 K-steps. Output into padded f16 volume.
__global__ __launch_bounds__(256) void k_gemm1(const float* __restrict__ x,
                                               const f16* __restrict__ w1h,
                                               const float* __restrict__ fc1b,
                                               f16* __restrict__ h1p) {
  constexpr int LDA = 168;            // padded row stride (bank spread)
  __shared__ f16 lsA[128 * LDA];      // 43,008 B
  __shared__ f16 lsB[128 * 32];       // 8,192 B
  const int tid = threadIdx.x;
  const int lane = tid & 63, wave = tid >> 6;
  const int row0 = blockIdx.x * 128;
  const int wr = wave >> 1, wc = wave & 1;
  const int rl = lane & 15, kb = (lane >> 4) * 8;

  // stage A once: 128 rows x 160 cols, shift(H) fused, f32 -> f16
#pragma unroll
  for (int i = 0; i < 20; ++i) {
    int c = i * 256 + tid;            // 0..5119
    int row = c / 40;
    int q = c - row * 40;
    int ch0 = q * 4;
    int ks = ch0 >> 5;
    int s = ks - 2;
    int t = row0 + row;
    int h = (t >> 10) & 31;
    int hs = h - s;
    float4 v = {0.f, 0.f, 0.f, 0.f};
    if (hs >= 0 && hs < 32)
      v = *(const float4*)&x[(long)(t - s * 1024) * CIN + ch0];
    f16x4 o4;
    o4[0] = (f16)v.x; o4[1] = (f16)v.y; o4[2] = (f16)v.z; o4[3] = (f16)v.w;
    *(f16x4*)&lsA[row * LDA + ch0] = o4;
  }
  __syncthreads();

  for (int nt = 0; nt < 5; ++nt) {
    const int col0 = nt * 128;
    f32x4 acc[4][4] = {};
    for (int ks = 0; ks < 5; ++ks) {
      // stage B tile (128 x 32) from w1h
#pragma unroll
      for (int issue = 0; issue < 2; ++issue) {
        int c = issue * 256 + tid;
        int br = c >> 2;
        int kc = (c & 3) * 8;
        const f16* src = w1h + (size_t)(col0 + br) * CIN + ks * 32 + kc;
        async16(src, (char*)lsB + issue * 4096 + wave * 1024);
      }
      __syncthreads();
      f16x8 af[4], bfr[4];
#pragma unroll
      for (int mi = 0; mi < 4; ++mi)
        af[mi] = *(const f16x8*)&lsA[(wr * 64 + mi * 16 + rl) * LDA + ks * 32 + kb];
#pragma unroll
      for (int ni = 0; ni < 4; ++ni)
        bfr[ni] = *(const f16x8*)&lsB[(wc * 64 + ni * 16 + rl) * 32 + kb];
#pragma unroll
      for (int mi = 0; mi < 4; ++mi)
#pragma unroll
        for (int ni = 0; ni < 4; ++ni)
          acc[mi][ni] = __builtin_amdgcn_mfma_f32_16x16x32_f16(af[mi], bfr[ni], acc[mi][ni], 0, 0, 0);
      __syncthreads();
    }
    // epilogue: padded write (quads are d-aligned)
    const int rq = lane >> 4;
#pragma unroll
    for (int mi = 0; mi < 4; ++mi) {
      int rowq = row0 + wr * 64 + mi * 16 + rq * 4;
      int bq = rowq >> 15;
      int nq = rowq & 32767;
      int hq = nq >> 10, wq = (nq >> 5) & 31, dq = nq & 31;
      size_t pos = (size_t)((bq * PD + hq + 1) * PD + (wq + 1)) * PD + (dq + 1);
      f16* dst0 = h1p + pos * CHH;
#pragma unroll
      for (int ni = 0; ni < 4; ++ni) {
        int col = col0 + wc * 64 + ni * 16 + rl;
        float bias = fc1b[col];
#pragma unroll
        for (int r = 0; r < 4; ++r)
          dst0[(size_t)r * CHH + col] = (f16)(acc[mi][ni][r] + bias);
      }
    }
  }
}

// ---- depthwise 3x3x3 conv + bias + GELU (v6: f16 end-to-end, plane prefetch) ----
__global__ __launch_bounds__(256) void k_conv(const f16* __restrict__ h1p,
                                              const f16* __restrict__ wTh,
                                              const float* __restrict__ dwb,
                                              f16* __restrict__ h2h) {
  __shared__ f16 lw[27 * 64];
  __shared__ f16 lb[64];
  const int tid = threadIdx.x;
  const int cg = blockIdx.y;     // 0..9
#pragma unroll
  for (int i = 0; i < 7; ++i) {
    int idx = i * 256 + tid;
    if (idx < 27 * 64) lw[idx] = wTh[(idx >> 6) * CHH + cg * 64 + (idx & 63)];
  }
  if (tid < 64) lb[tid] = (f16)dwb[cg * 64 + tid];
  __syncthreads();

  const int lane = tid & 63, wave = tid >> 6;
  const int line = blockIdx.x * 4 + wave;   // b*1024 + h*32 + w
  const int c8 = lane & 7, dq = lane >> 3;
  const int d0 = dq * 4;
  const int ch0 = cg * 64 + c8 * 8;
  const int w = line & 31, h = (line >> 5) & 31, b = line >> 10;

  const size_t cidx = (size_t)((b * PD + h) * PD + w) * PD + d0;
  const f16* base = h1p + cidx * CHH + ch0;

  f16x8 acc[4];
  {
    f16x8 binit = *(const f16x8*)&lb[c8 * 8];
    acc[0] = binit; acc[1] = binit; acc[2] = binit; acc[3] = binit;
  }

  f16x8 v[6], vn[6];
#pragma unroll
  for (int j = 0; j < 6; ++j)
    v[j] = *(const f16x8*)(base + (size_t)j * CHH);

#pragma unroll
  for (int p = 0; p < 9; ++p) {
    const int kz = p / 3, ky = p % 3;
    if (p < 8) {                      // prefetch next plane
      const int kz2 = (p + 1) / 3, ky2 = (p + 1) % 3;
      const f16* pb2 = base + (size_t)(kz2 * PD + ky2) * PD * CHH;
#pragma unroll
      for (int j = 0; j < 6; ++j)
        vn[j] = *(const f16x8*)(pb2 + (size_t)j * CHH);
    }
    f16x8 wt0 = *(const f16x8*)&lw[((kz * 9 + ky * 3 + 0) << 6) + c8 * 8];
    f16x8 wt1 = *(const f16x8*)&lw[((kz * 9 + ky * 3 + 1) << 6) + c8 * 8];
    f16x8 wt2 = *(const f16x8*)&lw[((kz * 9 + ky * 3 + 2) << 6) + c8 * 8];
#pragma unroll
    for (int o = 0; o < 4; ++o) {
      acc[o] = v[o] * wt0 + acc[o];
      acc[o] = v[o + 1] * wt1 + acc[o];
      acc[o] = v[o + 2] * wt2 + acc[o];
    }
#pragma unroll
    for (int j = 0; j < 6; ++j) v[j] = vn[j];
  }

  const ptrdiff_t obase = (ptrdiff_t)(line * 32 + d0) * CHH + ch0;
#pragma unroll
  for (int o = 0; o < 4; ++o) {
    f16x8 xa = acc[o];
    f16x8 ov;
#pragma unroll
    for (int j = 0; j < 8; j += 2) {
      float g01[2];
#pragma unroll
      for (int u2 = 0; u2 < 2; ++u2) {
        float xv = (float)xa[j + u2];
        float x2 = xv * xv;
        float uu = xv * (2.3022078f + 0.102943324f * x2);
        float e = __builtin_exp2f(uu);
        float r = __builtin_amdgcn_rcpf(1.0f + e);
        g01[u2] = xv - xv * r;      // = x*sigmoid(2z), tanh-form gelu
      }
      f16x2 pk = __builtin_bit_cast(f16x2, __builtin_amdgcn_cvt_pkrtz(g01[0], g01[1]));
      ov[j] = pk[0]; ov[j + 1] = pk[1];
    }
    *(f16x8*)&h2h[obase + (ptrdiff_t)o * CHH] = ov;
  }
}

// ---- GEMM2: out[t,o] = sum_ch hs[t,ch]*fc2_w[o,ch] + fc2_b[o], shift(W) fused ----
// tile 128(M) x 160(N full), BK=64, K=640 (10 steps). f16 MFMA.
__global__ __launch_bounds__(256) void k_gemm2(const f16* __restrict__ h2h,
                                               const f16* __restrict__ w2h,
                                               const float* __restrict__ fc2b,
                                               const f16* __restrict__ zp,
                                               float* __restrict__ out) {
  __shared__ f16 lsA[128 * 64];  // 16KB
  __shared__ f16 lsB[160 * 64];  // 20KB
  const int tid = threadIdx.x, lane = tid & 63, wave = tid >> 6;
  const int row0 = blockIdx.x * 128;
  const int rl = lane & 15, kb = (lane >> 4) * 8;

  f32x4 acc[2][10] = {};

  for (int kt = 0; kt < 10; ++kt) {
    __syncthreads();
    const int k0 = kt * 64;
    const int s = (k0 >> 7) - 2;  // shift for 128-channel chunk; uniform per 64-K slice
#pragma unroll
    for (int issue = 0; issue < 4; ++issue) {
      int c = issue * 256 + tid;
      int ar = c >> 3;
      int kc = (c & 7) * 8;
      int t = row0 + ar;
      int w = (t >> 5) & 31;
      int wsv = w - s;
      const f16* src;
      if (wsv >= 0 && wsv < 32)
        src = h2h + (size_t)(t - s * 32) * CHH + k0 + kc;
      else
        src = zp + (size_t)(c & 63) * 8;
      async16(src, (char*)lsA + issue * 4096 + wave * 1024);
    }
#pragma unroll
    for (int issue = 0; issue < 5; ++issue) {
      int c = issue * 256 + tid;
      int br = c >> 3;
      int kc = (c & 7) * 8;
      const f16* src = w2h + (size_t)br * CHH + k0 + kc;
      async16(src, (char*)lsB + issue * 4096 + wave * 1024);
    }
    __syncthreads();
#pragma unroll
    for (int kk = 0; kk < 2; ++kk) {
      f16x8 af[2], bfr[10];
#pragma unroll
      for (int mi = 0; mi < 2; ++mi)
        af[mi] = *(const f16x8*)&lsA[(wave * 32 + mi * 16 + rl) * 64 + kk * 32 + kb];
#pragma unroll
      for (int ni = 0; ni < 10; ++ni)
        bfr[ni] = *(const f16x8*)&lsB[(ni * 16 + rl) * 64 + kk * 32 + kb];
#pragma unroll
      for (int mi = 0; mi < 2; ++mi)
#pragma unroll
        for (int ni = 0; ni < 10; ++ni)
          acc[mi][ni] = __builtin_amdgcn_mfma_f32_16x16x32_f16(af[mi], bfr[ni], acc[mi][ni], 0, 0, 0);
    }
  }
  const int rq = lane >> 4;
#pragma unroll
  for (int mi = 0; mi < 2; ++mi) {
#pragma unroll
    for (int ni = 0; ni < 10; ++ni) {
      int col = ni * 16 + rl;
      float bias = fc2b[col];
#pragma unroll
      for (int r = 0; r < 4; ++r) {
        int row = row0 + wave * 32 + mi * 16 + rq * 4 + r;
        out[(size_t)row * CIN + col] = acc[mi][ni][r] + bias;
      }
    }
  }
}

extern "C" void kernel_launch(void* const* d_in, const int* in_sizes, int n_in,
                              void* d_out, int out_size, void* d_ws, size_t ws_size,
                              hipStream_t stream) {
  const float* x    = (const float*)d_in[0];
  const float* fc1w = (const float*)d_in[1];
  const float* fc1b = (const float*)d_in[2];
  const float* dww  = (const float*)d_in[3];
  const float* dwb  = (const float*)d_in[4];
  const float* fc2w = (const float*)d_in[5];
  const float* fc2b = (const float*)d_in[6];

  char* ws = (char*)d_ws;
  f16* w1h  = (f16*)(ws + W1_OFF);
  f16* w2h  = (f16*)(ws + W2_OFF);
  f16* wTh  = (f16*)(ws + WTH_OFF);
  f16* zp   = (f16*)(ws + ZP_OFF);
  f16* h2h  = (f16*)(ws + U_OFF);
  f16* h1p  = (f16*)(ws + H1P_OFF);
  float* out = (float*)d_out;

  k_zero_pad<<<(2 * PT * 80) / 256, 256, 0, stream>>>(h1p);
  k_prep_w<<<876, 256, 0, stream>>>(fc1w, fc2w, dww, w1h, w2h, wTh, (unsigned*)zp);
  k_gemm1<<<512, 256, 0, stream>>>(x, w1h, fc1b, h1p);
  dim3 gc(BN / 32 / 4, 10);
  k_conv<<<gc, 256, 0, stream>>>(h1p, wTh, dwb, h2h);
  k_gemm2<<<512, 256, 0, stream>>>(h2h, w2h, fc2b, zp, out);
}

// Round 8
// 141.546 us; speedup vs baseline: 1.1074x; 1.1074x over previous
//
#include <hip/hip_runtime.h>
#include <hip/hip_bf16.h>
#include <math.h>

#define DEVI __device__ __forceinline__

typedef _Float16 f16;
typedef f16 f16x2 __attribute__((ext_vector_type(2)));
typedef f16 f16x4 __attribute__((ext_vector_type(4)));
typedef f16 f16x8 __attribute__((ext_vector_type(8)));
typedef float f32x4 __attribute__((ext_vector_type(4)));

// ---- problem dims (fixed) ----
constexpr int Bb = 2, Hh = 32, Ww = 32, Dd = 32;
constexpr int Nn = Hh * Ww * Dd;      // 32768
constexpr int BN = Bb * Nn;           // 65536 tokens
constexpr int CIN = 160, CHH = 640;
constexpr int PD = 34;                // padded dim
constexpr int PT = PD * PD * PD;      // 39304 padded tokens per batch

// ---- workspace layout (bytes) ----
constexpr size_t W1_OFF  = 0;                                   // fc1_w f16: 204,800
constexpr size_t W2_OFF  = W1_OFF + (size_t)CHH * CIN * 2;      // fc2_w f16: 204,800
constexpr size_t WTH_OFF = W2_OFF + (size_t)CIN * CHH * 2;      // dw_w f16 [27][640]: 34,560
constexpr size_t ZP_OFF  = WTH_OFF + 34816;                     // zero page: 8,192
constexpr size_t U_OFF   = 458752;                              // h2 f16: 83,886,080
constexpr size_t H1P_OFF = U_OFF + (size_t)BN * CHH * 2;        // h1 padded f16: 100,618,240

DEVI void async16(const void* g, void* l) {
  __builtin_amdgcn_global_load_lds(
      (const __attribute__((address_space(1))) void*)g,
      (__attribute__((address_space(3))) void*)l, 16, 0, 0);
}

// ---- prep: weights -> f16, dw_w transpose -> f16, zero page ----
__global__ __launch_bounds__(256) void k_prep_w(const float* __restrict__ fc1w,
                                                const float* __restrict__ fc2w,
                                                const float* __restrict__ dww,
                                                f16* __restrict__ w1h,
                                                f16* __restrict__ w2h,
                                                f16* __restrict__ wTh,
                                                unsigned* __restrict__ zp) {
  int i = blockIdx.x * 256 + threadIdx.x;
  const int NW = CHH * CIN;  // 102400
  if (i < NW) {
    w1h[i] = (f16)fc1w[i];
  } else if (i < 2 * NW) {
    int j = i - NW;
    w2h[j] = (f16)fc2w[j];
  } else if (i < 2 * NW + 27 * CHH) {
    int j = i - 2 * NW;
    int ch = j / 27, tap = j % 27;
    wTh[tap * CHH + ch] = (f16)dww[j];
  } else if (i < 2 * NW + 27 * CHH + 2048) {
    zp[i - (2 * NW + 27 * CHH)] = 0u;
  }
}

// ---- zero the pad shell of the padded h1 volume (no input deps) ----
__global__ __launch_bounds__(256) void k_zero_pad(f16* __restrict__ h1p) {
  int g = blockIdx.x * 256 + threadIdx.x;   // over 2*PT*80
  int p = g / 80;
  int c = g - p * 80;
  if (p >= 2 * PT) return;
  int r = p % PT;
  int hp = r / (PD * PD);
  int r2 = r % (PD * PD);
  int wp = r2 / PD, dp = r2 % PD;
  bool pad = (hp == 0) | (hp == PD - 1) | (wp == 0) | (wp == PD - 1) |
             (dp == 0) | (dp == PD - 1);
  if (!pad) return;
  f16x8 z = {};
  *(f16x8*)&h1p[(size_t)p * CHH + c * 8] = z;
}

// ---- GEMM1 (fused x-convert + shift(H)): h1p = fc1 of shifted x ----
// Block: M=128 full-K A-panel staged ONCE in LDS (f32->f16 cvt in staging),
// then loops 5 N-tiles x 5 K-steps. Output into padded f16 volume.
__global__ __launch_bounds__(256) void k_gemm1(const float* __restrict__ x,
                                               const f16* __restrict__ w1h,
                                               const float* __restrict__ fc1b,
                                               f16* __restrict__ h1p) {
  constexpr int LDA = 168;            // padded row stride (bank spread)
  __shared__ f16 lsA[128 * LDA];      // 43,008 B
  __shared__ f16 lsB[128 * 32];       // 8,192 B
  const int tid = threadIdx.x;
  const int lane = tid & 63, wave = tid >> 6;
  const int row0 = blockIdx.x * 128;
  const int wr = wave >> 1, wc = wave & 1;
  const int rl = lane & 15, kb = (lane >> 4) * 8;

  // stage A once: 128 rows x 160 cols, shift(H) fused, f32 -> f16
#pragma unroll
  for (int i = 0; i < 20; ++i) {
    int c = i * 256 + tid;            // 0..5119
    int row = c / 40;
    int q = c - row * 40;
    int ch0 = q * 4;
    int ks = ch0 >> 5;
    int s = ks - 2;
    int t = row0 + row;
    int h = (t >> 10) & 31;
    int hs = h - s;
    float4 v = {0.f, 0.f, 0.f, 0.f};
    if (hs >= 0 && hs < 32)
      v = *(const float4*)&x[(long)(t - s * 1024) * CIN + ch0];
    f16x4 o4;
    o4[0] = (f16)v.x; o4[1] = (f16)v.y; o4[2] = (f16)v.z; o4[3] = (f16)v.w;
    *(f16x4*)&lsA[row * LDA + ch0] = o4;
  }
  __syncthreads();

  for (int nt = 0; nt < 5; ++nt) {
    const int col0 = nt * 128;
    f32x4 acc[4][4] = {};
    for (int ks = 0; ks < 5; ++ks) {
      // stage B tile (128 x 32) from w1h
#pragma unroll
      for (int issue = 0; issue < 2; ++issue) {
        int c = issue * 256 + tid;
        int br = c >> 2;
        int kc = (c & 3) * 8;
        const f16* src = w1h + (size_t)(col0 + br) * CIN + ks * 32 + kc;
        async16(src, (char*)lsB + issue * 4096 + wave * 1024);
      }
      __syncthreads();
      f16x8 af[4], bfr[4];
#pragma unroll
      for (int mi = 0; mi < 4; ++mi)
        af[mi] = *(const f16x8*)&lsA[(wr * 64 + mi * 16 + rl) * LDA + ks * 32 + kb];
#pragma unroll
      for (int ni = 0; ni < 4; ++ni)
        bfr[ni] = *(const f16x8*)&lsB[(wc * 64 + ni * 16 + rl) * 32 + kb];
#pragma unroll
      for (int mi = 0; mi < 4; ++mi)
#pragma unroll
        for (int ni = 0; ni < 4; ++ni)
          acc[mi][ni] = __builtin_amdgcn_mfma_f32_16x16x32_f16(af[mi], bfr[ni], acc[mi][ni], 0, 0, 0);
      __syncthreads();
    }
    // epilogue: padded write (quads are d-aligned)
    const int rq = lane >> 4;
#pragma unroll
    for (int mi = 0; mi < 4; ++mi) {
      int rowq = row0 + wr * 64 + mi * 16 + rq * 4;
      int bq = rowq >> 15;
      int nq = rowq & 32767;
      int hq = nq >> 10, wq = (nq >> 5) & 31, dq = nq & 31;
      size_t pos = (size_t)((bq * PD + hq + 1) * PD + (wq + 1)) * PD + (dq + 1);
      f16* dst0 = h1p + pos * CHH;
#pragma unroll
      for (int ni = 0; ni < 4; ++ni) {
        int col = col0 + wc * 64 + ni * 16 + rl;
        float bias = fc1b[col];
#pragma unroll
        for (int r = 0; r < 4; ++r)
          dst0[(size_t)r * CHH + col] = (f16)(acc[mi][ni][r] + bias);
      }
    }
  }
}

// ---- depthwise 3x3x3 conv + bias + GELU (v7: v5 load-at-use structure, f16) ----
// block = 256 = 4 waves; wave = one (b,h,w) line: 8 c8 x 8 dq (4 d-outputs each).
// grid = (BN/32/4, 10 ch-groups). All 54 tap loads unconditional, const offsets.
__global__ __launch_bounds__(256) void k_conv(const f16* __restrict__ h1p,
                                              const f16* __restrict__ wTh,
                                              const float* __restrict__ dwb,
                                              f16* __restrict__ h2h) {
  __shared__ f16 lw[27 * 64];
  __shared__ f16 lb[64];
  const int tid = threadIdx.x;
  const int cg = blockIdx.y;     // 0..9
#pragma unroll
  for (int i = 0; i < 7; ++i) {
    int idx = i * 256 + tid;
    if (idx < 27 * 64) lw[idx] = wTh[(idx >> 6) * CHH + cg * 64 + (idx & 63)];
  }
  if (tid < 64) lb[tid] = (f16)dwb[cg * 64 + tid];
  __syncthreads();

  const int lane = tid & 63, wave = tid >> 6;
  const int line = blockIdx.x * 4 + wave;   // b*1024 + h*32 + w
  const int c8 = lane & 7, dq = lane >> 3;
  const int d0 = dq * 4;
  const int ch0 = cg * 64 + c8 * 8;
  const int w = line & 31, h = (line >> 5) & 31, b = line >> 10;

  const size_t cidx = (size_t)((b * PD + h) * PD + w) * PD + d0;
  const f16* base = h1p + cidx * CHH + ch0;

  f16x8 acc[4];
  {
    f16x8 binit = *(const f16x8*)&lb[c8 * 8];
    acc[0] = binit; acc[1] = binit; acc[2] = binit; acc[3] = binit;
  }

#pragma unroll
  for (int kz = 0; kz < 3; ++kz) {
#pragma unroll
    for (int ky = 0; ky < 3; ++ky) {
      const f16* pb = base + (size_t)(kz * PD + ky) * PD * CHH;
      f16x8 wt[3];
#pragma unroll
      for (int kx = 0; kx < 3; ++kx)
        wt[kx] = *(const f16x8*)&lw[((kz * 9 + ky * 3 + kx) << 6) + c8 * 8];
      f16x8 v[6];
#pragma unroll
      for (int j = 0; j < 6; ++j)
        v[j] = *(const f16x8*)(pb + (size_t)j * CHH);
#pragma unroll
      for (int o = 0; o < 4; ++o)
#pragma unroll
        for (int kx = 0; kx < 3; ++kx)
          acc[o] = v[o + kx] * wt[kx] + acc[o];   // v_pk_fma_f16
    }
  }

  const ptrdiff_t obase = (ptrdiff_t)(line * 32 + d0) * CHH + ch0;
#pragma unroll
  for (int o = 0; o < 4; ++o) {
    f16x8 xa = acc[o];
    f16x8 ov;
#pragma unroll
    for (int j = 0; j < 8; j += 2) {
      float g01[2];
#pragma unroll
      for (int u2 = 0; u2 < 2; ++u2) {
        float xv = (float)xa[j + u2];
        float x2 = xv * xv;
        float uu = xv * (2.3022078f + 0.102943324f * x2);
        float e = __builtin_exp2f(uu);
        float r = __builtin_amdgcn_rcpf(1.0f + e);
        g01[u2] = xv - xv * r;      // tanh-form gelu, div-free
      }
      f16x2 pk = __builtin_bit_cast(f16x2, __builtin_amdgcn_cvt_pkrtz(g01[0], g01[1]));
      ov[j] = pk[0]; ov[j + 1] = pk[1];
    }
    *(f16x8*)&h2h[obase + (ptrdiff_t)o * CHH] = ov;
  }
}

// ---- GEMM2: out[t,o] = sum_ch hs[t,ch]*fc2_w[o,ch] + fc2_b[o], shift(W) fused ----
// tile 128(M) x 160(N full), BK=64, K=640 (10 steps). f16 MFMA.
__global__ __launch_bounds__(256) void k_gemm2(const f16* __restrict__ h2h,
                                               const f16* __restrict__ w2h,
                                               const float* __restrict__ fc2b,
                                               const f16* __restrict__ zp,
                                               float* __restrict__ out) {
  __shared__ f16 lsA[128 * 64];  // 16KB
  __shared__ f16 lsB[160 * 64];  // 20KB
  const int tid = threadIdx.x, lane = tid & 63, wave = tid >> 6;
  const int row0 = blockIdx.x * 128;
  const int rl = lane & 15, kb = (lane >> 4) * 8;

  f32x4 acc[2][10] = {};

  for (int kt = 0; kt < 10; ++kt) {
    __syncthreads();
    const int k0 = kt * 64;
    const int s = (k0 >> 7) - 2;  // shift for 128-channel chunk; uniform per 64-K slice
#pragma unroll
    for (int issue = 0; issue < 4; ++issue) {
      int c = issue * 256 + tid;
      int ar = c >> 3;
      int kc = (c & 7) * 8;
      int t = row0 + ar;
      int w = (t >> 5) & 31;
      int wsv = w - s;
      const f16* src;
      if (wsv >= 0 && wsv < 32)
        src = h2h + (size_t)(t - s * 32) * CHH + k0 + kc;
      else
        src = zp + (size_t)(c & 63) * 8;
      async16(src, (char*)lsA + issue * 4096 + wave * 1024);
    }
#pragma unroll
    for (int issue = 0; issue < 5; ++issue) {
      int c = issue * 256 + tid;
      int br = c >> 3;
      int kc = (c & 7) * 8;
      const f16* src = w2h + (size_t)br * CHH + k0 + kc;
      async16(src, (char*)lsB + issue * 4096 + wave * 1024);
    }
    __syncthreads();
#pragma unroll
    for (int kk = 0; kk < 2; ++kk) {
      f16x8 af[2], bfr[10];
#pragma unroll
      for (int mi = 0; mi < 2; ++mi)
        af[mi] = *(const f16x8*)&lsA[(wave * 32 + mi * 16 + rl) * 64 + kk * 32 + kb];
#pragma unroll
      for (int ni = 0; ni < 10; ++ni)
        bfr[ni] = *(const f16x8*)&lsB[(ni * 16 + rl) * 64 + kk * 32 + kb];
#pragma unroll
      for (int mi = 0; mi < 2; ++mi)
#pragma unroll
        for (int ni = 0; ni < 10; ++ni)
          acc[mi][ni] = __builtin_amdgcn_mfma_f32_16x16x32_f16(af[mi], bfr[ni], acc[mi][ni], 0, 0, 0);
    }
  }
  const int rq = lane >> 4;
#pragma unroll
  for (int mi = 0; mi < 2; ++mi) {
#pragma unroll
    for (int ni = 0; ni < 10; ++ni) {
      int col = ni * 16 + rl;
      float bias = fc2b[col];
#pragma unroll
      for (int r = 0; r < 4; ++r) {
        int row = row0 + wave * 32 + mi * 16 + rq * 4 + r;
        out[(size_t)row * CIN + col] = acc[mi][ni][r] + bias;
      }
    }
  }
}

extern "C" void kernel_launch(void* const* d_in, const int* in_sizes, int n_in,
                              void* d_out, int out_size, void* d_ws, size_t ws_size,
                              hipStream_t stream) {
  const float* x    = (const float*)d_in[0];
  const float* fc1w = (const float*)d_in[1];
  const float* fc1b = (const float*)d_in[2];
  const float* dww  = (const float*)d_in[3];
  const float* dwb  = (const float*)d_in[4];
  const float* fc2w = (const float*)d_in[5];
  const float* fc2b = (const float*)d_in[6];

  char* ws = (char*)d_ws;
  f16* w1h  = (f16*)(ws + W1_OFF);
  f16* w2h  = (f16*)(ws + W2_OFF);
  f16* wTh  = (f16*)(ws + WTH_OFF);
  f16* zp   = (f16*)(ws + ZP_OFF);
  f16* h2h  = (f16*)(ws + U_OFF);
  f16* h1p  = (f16*)(ws + H1P_OFF);
  float* out = (float*)d_out;

  k_zero_pad<<<(2 * PT * 80) / 256, 256, 0, stream>>>(h1p);
  k_prep_w<<<876, 256, 0, stream>>>(fc1w, fc2w, dww, w1h, w2h, wTh, (unsigned*)zp);
  k_gemm1<<<512, 256, 0, stream>>>(x, w1h, fc1b, h1p);
  dim3 gc(BN / 32 / 4, 10);
  k_conv<<<gc, 256, 0, stream>>>(h1p, wTh, dwb, h2h);
  k_gemm2<<<512, 256, 0, stream>>>(h2h, w2h, fc2b, zp, out);
}